// Round 4
// baseline (77.052 us; speedup 1.0000x reference)
//
#include <hip/hip_runtime.h>
#include <hip/hip_bf16.h>

#define BHN 32      // B*H
#define SEQ 4096
#define DIM 128
#define TROWS 64               // rows per LDS tile

typedef __bf16 bf16x8 __attribute__((ext_vector_type(8)));
typedef __bf16 bf16x4 __attribute__((ext_vector_type(4)));
typedef float  f32x4  __attribute__((ext_vector_type(4)));

__device__ __forceinline__ bf16x8 cvt8(const float* f) {
    bf16x8 r;
#pragma unroll
    for (int i = 0; i < 8; ++i) r[i] = (__bf16)f[i];
    return r;
}

// ---------------------------------------------------------------------------
// Phase 1 (8-wave): partial kv^T. C[e][d] = sum_s v[s][e]*k[s][d]
//
// OCCUPANCY MODEL (rebuilt from R0-R3 counters):
//   R1: 32V+32A=64/wave -> 4 blocks/CU -> occ 64-70%  (grid CH=32 offered 4)
//   R0: grid 512 = 2.0 blocks/CU BY GRID -> occ 34%   (grid-capped, not regs)
//   R2: CH=32 grid offered 4; 52V(granule->~56-64)+32A ~= 88-96 -> 5 w/SIMD
//       -> 20 waves -> quantized to TWO 8-wave blocks -> occ 32%. One granule
//       over the knee.
//   3-block knee: total <= 512/6 ~ 85 regs; AGPR fixed 32 -> need VGPR <= 48.
//
// R4 changes:
//  (1) CH=32 grid (1024 blocks, offers 4/CU).
//  (2) SPLIT k/v staging: load k -> pack k -> sched_barrier -> load v ->
//      pack v. Peak staging 32 -> 16 regs; target VGPR <= 48 -> 3 blocks/CU.
//      sched_barrier(0) stops the compiler hoisting v-loads back over pack-k
//      (R3 lesson: compiler freely re-schedules reg-carried global loads).
//      Service-rate-bound => serialized v-wait costs no extra bytes-time.
//  (3) Contiguous chunk mapping restored (R3 interleave = 8x L2-fill
//      amplification across XCDs, +14% dur).
//
// LDS swizzle unchanged: elem (d,s) at d*64 + (((s>>3) ^ key(d))*8) + (s&7),
//   key(d) = (d&7) ^ ((d>>2)&7)  -> <=2-way on both write and read lanes.
// ---------------------------------------------------------------------------
template<int CH>
__global__ __launch_bounds__(512) void p1_kv(const float* __restrict__ kin,
                                             const float* __restrict__ vin,
                                             __bf16* __restrict__ ws1) {
    constexpr int SR = SEQ / CH;       // rows per block (128 at CH=32)
    constexpr int NT = SR / TROWS;     // tiles per block (2 at CH=32)

    __shared__ __align__(16) __bf16 kt[DIM][TROWS];  // 16 KB
    __shared__ __align__(16) __bf16 vt[DIM][TROWS];  // 16 KB

    const int bh    = blockIdx.x / CH;
    const int chunk = blockIdx.x % CH;
    const int tid = threadIdx.x;

    const int dcol = tid & 31;     // d-quad index 0..31  -> d0 = dcol*4
    const int sgrp = tid >> 5;     // s-quad index 0..15  -> s0 = sgrp*4
    const int d0 = dcol * 4;
    const int s0 = sgrp * 4;

    const int w = tid >> 6;
    const int l = tid & 63;
    const int g = l >> 4;
    const int c = l & 15;

    const float* kb = kin + (size_t)bh * SEQ * DIM + (size_t)chunk * SR * DIM;
    const float* vb = vin + (size_t)bh * SEQ * DIM + (size_t)chunk * SR * DIM;

    f32x4 acc[8];
#pragma unroll
    for (int nt = 0; nt < 8; ++nt) acc[nt] = (f32x4){0.f, 0.f, 0.f, 0.f};

    for (int t = 0; t < NT; ++t) {
        const size_t off = ((size_t)(t * TROWS + s0)) * DIM + d0;

        // ---- K: load 4 rows x 16B, pack into swizzled LDS, release regs
        {
            f32x4 kr[4];
#pragma unroll
            for (int j = 0; j < 4; ++j) kr[j] = *(const f32x4*)(kb + off + j * DIM);
#pragma unroll
            for (int jd = 0; jd < 4; ++jd) {
                const int dd  = d0 + jd;
                const int key = (dd & 7) ^ ((dd >> 2) & 7);
                const int o   = (((sgrp >> 1) ^ key) * 8) + (sgrp & 1) * 4;
                bf16x4 pk;
#pragma unroll
                for (int j = 0; j < 4; ++j) pk[j] = (__bf16)kr[j][jd];
                *(bf16x4*)&kt[dd][o] = pk;
            }
        }
        // pin: v-loads may not be hoisted above the k-pack (keeps peak
        // staging at 16 regs, not 32)
        __builtin_amdgcn_sched_barrier(0);

        // ---- V: load 4 rows x 16B, pack into swizzled LDS
        {
            f32x4 vr[4];
#pragma unroll
            for (int j = 0; j < 4; ++j) vr[j] = *(const f32x4*)(vb + off + j * DIM);
#pragma unroll
            for (int jd = 0; jd < 4; ++jd) {
                const int dd  = d0 + jd;
                const int key = (dd & 7) ^ ((dd >> 2) & 7);
                const int o   = (((sgrp >> 1) ^ key) * 8) + (sgrp & 1) * 4;
                bf16x4 pv;
#pragma unroll
                for (int j = 0; j < 4; ++j) pv[j] = (__bf16)vr[j][jd];
                *(bf16x4*)&vt[dd][o] = pv;
            }
        }
        __syncthreads();

        // ---- MFMA: wave w owns e-strip [w*16, w*16+16); K-dim 64 s (2 steps)
        const int e    = w * 16 + c;
        const int keyE = (e & 7) ^ ((e >> 2) & 7);
#pragma unroll
        for (int st = 0; st < 2; ++st) {
            bf16x8 af = *(const bf16x8*)&vt[e][((st * 4 + g) ^ keyE) * 8];
#pragma unroll
            for (int nt = 0; nt < 8; ++nt) {
                const int d    = nt * 16 + c;
                const int keyD = (d & 7) ^ ((d >> 2) & 7);
                bf16x8 bfr = *(const bf16x8*)&kt[d][((st * 4 + g) ^ keyD) * 8];
                acc[nt] = __builtin_amdgcn_mfma_f32_16x16x32_bf16(af, bfr, acc[nt], 0, 0, 0);
            }
        }
        __syncthreads();
    }

    // store bf16 partials, MFMA-native flat layout: f = nt*2048 + tid*4 + r
    // (each bf16x4 store instr = 512B/wave contiguous burst)
    __bf16* outp = ws1 + ((size_t)chunk * BHN + bh) * (DIM * DIM);
#pragma unroll
    for (int nt = 0; nt < 8; ++nt) {
        bf16x4 p;
#pragma unroll
        for (int r = 0; r < 4; ++r) p[r] = (__bf16)acc[nt][r];
        *(bf16x4*)(outp + nt * 2048 + tid * 4) = p;
    }
}

// ---------------------------------------------------------------------------
// Phase 1.5: reduce CH bf16 partials (fp32 accum) -> bf16 kv^T swizzled for p2:
//   element (e,d) at  e*128 + ((d>>3)^(e&15))*8 + (d&7)
// Decode of p1's flat layout  f = nt*2048 + tid*4 + r, tid = w*64+g*16+c:
//   nt=f>>11; w=(f>>8)&7; g=(f>>6)&3; c=(f>>2)&15; r=f&3
//   e = w*16 + g*4 + r ;  d = nt*16 + c
// 256 blocks * 256 threads; thread owns 8 consecutive f (16B loads/chunk).
// ---------------------------------------------------------------------------
template<int CH>
__global__ __launch_bounds__(256) void p1_reduce(const __bf16* __restrict__ ws1,
                                                 __bf16* __restrict__ ws2) {
    const int t   = blockIdx.x * 256 + threadIdx.x;  // 65536 threads
    const int bh  = t >> 11;
    const int r11 = t & 2047;

    const __bf16* base = ws1 + (size_t)bh * (DIM * DIM) + r11 * 8;
    float s[8] = {0.f, 0.f, 0.f, 0.f, 0.f, 0.f, 0.f, 0.f};
#pragma unroll
    for (int ch = 0; ch < CH; ++ch) {
        bf16x8 a = *(const bf16x8*)(base + (size_t)ch * BHN * DIM * DIM);
#pragma unroll
        for (int i = 0; i < 8; ++i) s[i] += (float)a[i];
    }

    __bf16* dst = ws2 + (size_t)bh * (DIM * DIM);
#pragma unroll
    for (int i = 0; i < 8; ++i) {
        const int f  = r11 * 8 + i;
        const int nt = f >> 11;
        const int wv = (f >> 8) & 7;
        const int gg = (f >> 6) & 3;
        const int cc = (f >> 2) & 15;
        const int r  = f & 3;
        const int e  = wv * 16 + gg * 4 + r;
        const int d  = nt * 16 + cc;
        dst[e * DIM + (((d >> 3) ^ (e & 15)) * 8) + (d & 7)] = (__bf16)s[i];
    }
}

// ---------------------------------------------------------------------------
// Phase 2 (flipped operands): out[s][e] = v[s][e] + sum_d q[s][d] * kv[d][e]
// Compute C[e][s] = mfma(A = kv_frag (M=e), B = q_frag (N=s)).
// Each lane holds 4 CONSECUTIVE e per fragment -> f32x4 epilogue.
// grid = 32 heads * 32 row-chunks = 1024 blocks, 512 threads (8 waves).
// UNCHANGED: VGPR=32 -> 4 blocks/CU; near its streaming floor per counters.
// ---------------------------------------------------------------------------
__global__ __launch_bounds__(512) void p2_qkv(const float* __restrict__ qin,
                                              const float* __restrict__ vin,
                                              const __bf16* __restrict__ ws2,
                                              float* __restrict__ outp) {
    __shared__ __align__(16) __bf16 kvs[DIM * DIM];

    const int bh = blockIdx.x & 31;
    const int rc = blockIdx.x >> 5;
    const int tid = threadIdx.x;

    {   // linear 16B-copy of the (already swizzled) 32 KB head slab into LDS
        const uint4* src = (const uint4*)(ws2 + (size_t)bh * DIM * DIM);
        uint4* dst = (uint4*)kvs;
#pragma unroll
        for (int j = 0; j < 4; ++j) dst[tid + j * 512] = src[tid + j * 512];
    }
    __syncthreads();

    const int w = tid >> 6;
    const int l = tid & 63;
    const int g = l >> 4;
    const int c = l & 15;
    const int s = rc * 128 + w * 16 + c;     // this lane's output row

    // hoist all 4 Q fragments: B[d][s], lane holds q[s][ks*32 + g*8 .. +8)
    const float* qrow = qin + (size_t)bh * SEQ * DIM + (size_t)s * DIM + g * 8;
    bf16x8 bq[4];
#pragma unroll
    for (int ks = 0; ks < 4; ++ks) {
        f32x4 x = *(const f32x4*)(qrow + ks * 32);
        f32x4 y = *(const f32x4*)(qrow + ks * 32 + 4);
        float tmp[8];
        tmp[0]=x[0]; tmp[1]=x[1]; tmp[2]=x[2]; tmp[3]=x[3];
        tmp[4]=y[0]; tmp[5]=y[1]; tmp[6]=y[2]; tmp[7]=y[3];
        bq[ks] = cvt8(tmp);
    }

    f32x4 acc[8];
#pragma unroll
    for (int et = 0; et < 8; ++et) acc[et] = (f32x4){0.f, 0.f, 0.f, 0.f};

#pragma unroll
    for (int ks = 0; ks < 4; ++ks) {
#pragma unroll
        for (int et = 0; et < 8; ++et) {
            const int e = et * 16 + c;                 // A's M index = lane&15
            const int slot = (ks * 4 + g) ^ c;         // unswizzle: d-slice = ks*32+g*8
            bf16x8 a = *(const bf16x8*)&kvs[e * DIM + slot * 8];
            acc[et] = __builtin_amdgcn_mfma_f32_16x16x32_bf16(a, bq[ks], acc[et], 0, 0, 0);
        }
    }

    // epilogue: lane holds out[s][et*16 + g*4 .. +4) -> vectorized V add + store
    const float* vb = vin + (size_t)bh * SEQ * DIM;
    float* ob = outp + (size_t)bh * SEQ * DIM;
#pragma unroll
    for (int et = 0; et < 8; ++et) {
        const size_t idx = (size_t)s * DIM + et * 16 + g * 4;
        f32x4 vv = *(const f32x4*)(vb + idx);
        f32x4 o = acc[et] + vv;
        *(f32x4*)(ob + idx) = o;
    }
}

// ---------------------------------------------------------------------------
// Workspace layout (CH-independent offsets):
//   ws2 = d_ws + 0                      (1 MiB reduced kv, swizzled)
//   ws1 = d_ws + 1 MiB                  (CH * 1 MiB bf16 partials)
// CH=32 needs 33 MiB total (proven available in R1/R2); guarded fallback to
// CH=16 if the harness workspace is smaller.
// ---------------------------------------------------------------------------
extern "C" void kernel_launch(void* const* d_in, const int* in_sizes, int n_in,
                              void* d_out, int out_size, void* d_ws, size_t ws_size,
                              hipStream_t stream) {
    const float* q = (const float*)d_in[0];
    const float* k = (const float*)d_in[1];
    const float* v = (const float*)d_in[2];
    float* out = (float*)d_out;

    __bf16* ws2 = (__bf16*)d_ws;                                   // 1 MiB
    __bf16* ws1 = (__bf16*)d_ws + (size_t)BHN * DIM * DIM;         // partials

    const size_t slab = (size_t)BHN * DIM * DIM * sizeof(__bf16);  // 1 MiB
    if (ws_size >= slab * (1 + 32)) {
        p1_kv<32><<<BHN * 32, 512, 0, stream>>>(k, v, ws1);
        p1_reduce<32><<<256, 256, 0, stream>>>(ws1, ws2);
    } else {
        p1_kv<16><<<BHN * 16, 512, 0, stream>>>(k, v, ws1);
        p1_reduce<16><<<256, 256, 0, stream>>>(ws1, ws2);
    }
    p2_qkv<<<BHN * (SEQ / 128), 512, 0, stream>>>(q, v, ws2, out);
}

// Round 5
// 68.971 us; speedup vs baseline: 1.1172x; 1.1172x over previous
//
#include <hip/hip_runtime.h>
#include <hip/hip_bf16.h>

#define BHN 32      // B*H
#define SEQ 4096
#define DIM 128
#define TROWS 64               // rows per LDS tile

typedef __bf16 bf16x8 __attribute__((ext_vector_type(8)));
typedef __bf16 bf16x4 __attribute__((ext_vector_type(4)));
typedef float  f32x4  __attribute__((ext_vector_type(4)));

__device__ __forceinline__ bf16x8 cvt8(const float* f) {
    bf16x8 r;
#pragma unroll
    for (int i = 0; i < 8; ++i) r[i] = (__bf16)f[i];
    return r;
}

// ---------------------------------------------------------------------------
// Phase 1 (8-wave): partial kv^T. C[e][d] = sum_s v[s][e]*k[s][d]
//
// R4 POST-MORTEM: occ 32/44/66% across R0-R4 all give p1 ~48-56us ->
// occupancy lever DEAD. Invariant: combined traffic / dur ~= 2.9 TB/s every
// round (copy ubench: 6.3). Theory: burst duty-cycle -- block issues 64
// load-batches, sleeps at vmcnt(0)+syncthreads for the SLOWEST (max >> mean
// under queueing), MFMAs with zero demand, repeats -> ~50% demand duty.
//
// R5: continuous-demand pipeline the compiler cannot sink (R3 lesson):
//  (1) LDS DOUBLE-BUFFER kt/vt[2] (64 KB). One barrier per tile is provably
//      safe: pack(t+2) is only reachable after barrier(t+1), which implies
//      all waves finished MFMA(t) on that buffer.
//  (2) Register prefetch of tile t+1 issued AFTER pack(t) (regs just freed),
//      BEFORE MFMA(t), pinned by sched_barrier(0) fences (R4 proved the
//      fence is respected; R3's unfenced version was silently sunk).
//  (3) NO __syncthreads in the loop: "ds_write; s_waitcnt lgkmcnt(0);
//      s_barrier" via inline asm. __syncthreads may drain vmcnt(0) at the
//      barrier, which would kill the in-flight prefetch; lgkmcnt-only drain
//      is the canonical producer handoff and leaves global loads pending.
//  CH=16: 512 blocks, NT=4 -> prefetch covers 3/4 phases; 16 MB partials.
//
// LDS swizzle unchanged: elem (d,s) at d*64 + (((s>>3) ^ key(d))*8) + (s&7),
//   key(d) = (d&7) ^ ((d>>2)&7)  -> <=2-way on both write and read lanes.
// ---------------------------------------------------------------------------
template<int CH>
__global__ __launch_bounds__(512) void p1_kv(const float* __restrict__ kin,
                                             const float* __restrict__ vin,
                                             __bf16* __restrict__ ws1) {
    constexpr int SR = SEQ / CH;       // rows per block (256 at CH=16)
    constexpr int NT = SR / TROWS;     // tiles per block (4 at CH=16)

    __shared__ __align__(16) __bf16 kt[2][DIM][TROWS];  // 32 KB
    __shared__ __align__(16) __bf16 vt[2][DIM][TROWS];  // 32 KB

    const int bh    = blockIdx.x / CH;
    const int chunk = blockIdx.x % CH;
    const int tid = threadIdx.x;

    const int dcol = tid & 31;     // d-quad index 0..31  -> d0 = dcol*4
    const int sgrp = tid >> 5;     // s-quad index 0..15  -> s0 = sgrp*4
    const int d0 = dcol * 4;
    const int s0 = sgrp * 4;

    const int w = tid >> 6;
    const int l = tid & 63;
    const int g = l >> 4;
    const int c = l & 15;

    const float* kb = kin + (size_t)bh * SEQ * DIM + (size_t)chunk * SR * DIM;
    const float* vb = vin + (size_t)bh * SEQ * DIM + (size_t)chunk * SR * DIM;

    f32x4 acc[8];
#pragma unroll
    for (int nt = 0; nt < 8; ++nt) acc[nt] = (f32x4){0.f, 0.f, 0.f, 0.f};

    // single set of staging regs; refilled for t+1 right after pack(t)
    f32x4 kr[4], vr[4];
    {   // prologue: tile 0
        const size_t off = (size_t)s0 * DIM + d0;
#pragma unroll
        for (int j = 0; j < 4; ++j) {
            kr[j] = *(const f32x4*)(kb + off + j * DIM);
            vr[j] = *(const f32x4*)(vb + off + j * DIM);
        }
    }

#pragma unroll
    for (int t = 0; t < NT; ++t) {
        const int p = t & 1;   // compile-time after full unroll

        // ---- pack current tile (waits vmcnt for its loads internally)
#pragma unroll
        for (int jd = 0; jd < 4; ++jd) {
            const int dd  = d0 + jd;
            const int key = (dd & 7) ^ ((dd >> 2) & 7);
            const int o   = (((sgrp >> 1) ^ key) * 8) + (sgrp & 1) * 4;
            bf16x4 pk, pv;
#pragma unroll
            for (int j = 0; j < 4; ++j) {
                pk[j] = (__bf16)kr[j][jd];
                pv[j] = (__bf16)vr[j][jd];
            }
            *(bf16x4*)&kt[p][dd][o] = pk;
            *(bf16x4*)&vt[p][dd][o] = pv;
        }

        // ---- prefetch tile t+1 into the just-freed regs; fences pin it here
        __builtin_amdgcn_sched_barrier(0);
        if (t + 1 < NT) {
            const size_t off = ((size_t)((t + 1) * TROWS + s0)) * DIM + d0;
#pragma unroll
            for (int j = 0; j < 4; ++j) {
                kr[j] = *(const f32x4*)(kb + off + j * DIM);
                vr[j] = *(const f32x4*)(vb + off + j * DIM);
            }
        }
        __builtin_amdgcn_sched_barrier(0);

        // ---- producer handoff WITHOUT vmcnt drain: my ds_writes done, then
        //      block-wide barrier. Prefetch loads stay in flight.
        asm volatile("s_waitcnt lgkmcnt(0)" ::: "memory");
        __builtin_amdgcn_s_barrier();

        // ---- MFMA: wave w owns e-strip [w*16,+16); K-dim 64 s (2 steps)
        const int e    = w * 16 + c;
        const int keyE = (e & 7) ^ ((e >> 2) & 7);
#pragma unroll
        for (int st = 0; st < 2; ++st) {
            bf16x8 af = *(const bf16x8*)&vt[p][e][((st * 4 + g) ^ keyE) * 8];
#pragma unroll
            for (int nt = 0; nt < 8; ++nt) {
                const int d    = nt * 16 + c;
                const int keyD = (d & 7) ^ ((d >> 2) & 7);
                bf16x8 bfr = *(const bf16x8*)&kt[p][d][((st * 4 + g) ^ keyD) * 8];
                acc[nt] = __builtin_amdgcn_mfma_f32_16x16x32_bf16(af, bfr, acc[nt], 0, 0, 0);
            }
        }
        // no trailing barrier: next pack writes buffer p^1; a wave can only
        // reach pack of buffer p again after the NEXT barrier, which implies
        // all waves finished this MFMA.
    }

    // store bf16 partials, MFMA-native flat layout: f = nt*2048 + tid*4 + r
    // (each bf16x4 store instr = 512B/wave contiguous burst)
    __bf16* outp = ws1 + ((size_t)chunk * BHN + bh) * (DIM * DIM);
#pragma unroll
    for (int nt = 0; nt < 8; ++nt) {
        bf16x4 pq;
#pragma unroll
        for (int r = 0; r < 4; ++r) pq[r] = (__bf16)acc[nt][r];
        *(bf16x4*)(outp + nt * 2048 + tid * 4) = pq;
    }
}

// ---------------------------------------------------------------------------
// Phase 1.5: reduce CH bf16 partials (fp32 accum) -> bf16 kv^T swizzled for p2:
//   element (e,d) at  e*128 + ((d>>3)^(e&15))*8 + (d&7)
// Decode of p1's flat layout  f = nt*2048 + tid*4 + r, tid = w*64+g*16+c:
//   nt=f>>11; w=(f>>8)&7; g=(f>>6)&3; c=(f>>2)&15; r=f&3
//   e = w*16 + g*4 + r ;  d = nt*16 + c
// 256 blocks * 256 threads; thread owns 8 consecutive f (16B loads/chunk).
// ---------------------------------------------------------------------------
template<int CH>
__global__ __launch_bounds__(256) void p1_reduce(const __bf16* __restrict__ ws1,
                                                 __bf16* __restrict__ ws2) {
    const int t   = blockIdx.x * 256 + threadIdx.x;  // 65536 threads
    const int bh  = t >> 11;
    const int r11 = t & 2047;

    const __bf16* base = ws1 + (size_t)bh * (DIM * DIM) + r11 * 8;
    float s[8] = {0.f, 0.f, 0.f, 0.f, 0.f, 0.f, 0.f, 0.f};
#pragma unroll
    for (int ch = 0; ch < CH; ++ch) {
        bf16x8 a = *(const bf16x8*)(base + (size_t)ch * BHN * DIM * DIM);
#pragma unroll
        for (int i = 0; i < 8; ++i) s[i] += (float)a[i];
    }

    __bf16* dst = ws2 + (size_t)bh * (DIM * DIM);
#pragma unroll
    for (int i = 0; i < 8; ++i) {
        const int f  = r11 * 8 + i;
        const int nt = f >> 11;
        const int wv = (f >> 8) & 7;
        const int gg = (f >> 6) & 3;
        const int cc = (f >> 2) & 15;
        const int r  = f & 3;
        const int e  = wv * 16 + gg * 4 + r;
        const int d  = nt * 16 + cc;
        dst[e * DIM + (((d >> 3) ^ (e & 15)) * 8) + (d & 7)] = (__bf16)s[i];
    }
}

// ---------------------------------------------------------------------------
// Phase 2 (flipped operands): out[s][e] = v[s][e] + sum_d q[s][d] * kv[d][e]
// Compute C[e][s] = mfma(A = kv_frag (M=e), B = q_frag (N=s)).
// Each lane holds 4 CONSECUTIVE e per fragment -> f32x4 epilogue.
// grid = 32 heads * 32 row-chunks = 1024 blocks, 512 threads (8 waves).
// UNCHANGED: VGPR=32 -> 4 blocks/CU; per-wave independent main loop, no
// in-loop barriers; ~4.5 TB/s combined already (71% of copy ubench).
// ---------------------------------------------------------------------------
__global__ __launch_bounds__(512) void p2_qkv(const float* __restrict__ qin,
                                              const float* __restrict__ vin,
                                              const __bf16* __restrict__ ws2,
                                              float* __restrict__ outp) {
    __shared__ __align__(16) __bf16 kvs[DIM * DIM];

    const int bh = blockIdx.x & 31;
    const int rc = blockIdx.x >> 5;
    const int tid = threadIdx.x;

    {   // linear 16B-copy of the (already swizzled) 32 KB head slab into LDS
        const uint4* src = (const uint4*)(ws2 + (size_t)bh * DIM * DIM);
        uint4* dst = (uint4*)kvs;
#pragma unroll
        for (int j = 0; j < 4; ++j) dst[tid + j * 512] = src[tid + j * 512];
    }
    __syncthreads();

    const int w = tid >> 6;
    const int l = tid & 63;
    const int g = l >> 4;
    const int c = l & 15;
    const int s = rc * 128 + w * 16 + c;     // this lane's output row

    // hoist all 4 Q fragments: B[d][s], lane holds q[s][ks*32 + g*8 .. +8)
    const float* qrow = qin + (size_t)bh * SEQ * DIM + (size_t)s * DIM + g * 8;
    bf16x8 bq[4];
#pragma unroll
    for (int ks = 0; ks < 4; ++ks) {
        f32x4 x = *(const f32x4*)(qrow + ks * 32);
        f32x4 y = *(const f32x4*)(qrow + ks * 32 + 4);
        float tmp[8];
        tmp[0]=x[0]; tmp[1]=x[1]; tmp[2]=x[2]; tmp[3]=x[3];
        tmp[4]=y[0]; tmp[5]=y[1]; tmp[6]=y[2]; tmp[7]=y[3];
        bq[ks] = cvt8(tmp);
    }

    f32x4 acc[8];
#pragma unroll
    for (int et = 0; et < 8; ++et) acc[et] = (f32x4){0.f, 0.f, 0.f, 0.f};

#pragma unroll
    for (int ks = 0; ks < 4; ++ks) {
#pragma unroll
        for (int et = 0; et < 8; ++et) {
            const int e = et * 16 + c;                 // A's M index = lane&15
            const int slot = (ks * 4 + g) ^ c;         // unswizzle: d-slice = ks*32+g*8
            bf16x8 a = *(const bf16x8*)&kvs[e * DIM + slot * 8];
            acc[et] = __builtin_amdgcn_mfma_f32_16x16x32_bf16(a, bq[ks], acc[et], 0, 0, 0);
        }
    }

    // epilogue: lane holds out[s][et*16 + g*4 .. +4) -> vectorized V add + store
    const float* vb = vin + (size_t)bh * SEQ * DIM;
    float* ob = outp + (size_t)bh * SEQ * DIM;
#pragma unroll
    for (int et = 0; et < 8; ++et) {
        const size_t idx = (size_t)s * DIM + et * 16 + g * 4;
        f32x4 vv = *(const f32x4*)(vb + idx);
        f32x4 o = acc[et] + vv;
        *(f32x4*)(ob + idx) = o;
    }
}

// ---------------------------------------------------------------------------
// Workspace: ws2 (1 MiB reduced kv) + ws1 (16 x 1 MiB bf16 partials) = 17 MiB.
// ---------------------------------------------------------------------------
extern "C" void kernel_launch(void* const* d_in, const int* in_sizes, int n_in,
                              void* d_out, int out_size, void* d_ws, size_t ws_size,
                              hipStream_t stream) {
    const float* q = (const float*)d_in[0];
    const float* k = (const float*)d_in[1];
    const float* v = (const float*)d_in[2];
    float* out = (float*)d_out;

    __bf16* ws2 = (__bf16*)d_ws;                                   // 1 MiB
    __bf16* ws1 = (__bf16*)d_ws + (size_t)BHN * DIM * DIM;         // partials

    p1_kv<16><<<BHN * 16, 512, 0, stream>>>(k, v, ws1);
    p1_reduce<16><<<256, 256, 0, stream>>>(ws1, ws2);
    p2_qkv<<<BHN * (SEQ / 128), 512, 0, stream>>>(q, v, ws2, out);
}